// Round 1
// baseline (1852.701 us; speedup 1.0000x reference)
//
#include <hip/hip_runtime.h>
#include <stdint.h>

// Problem constants (reference: EMB=256, HID=1024, N_TRACKS=4096, SEQ=9, n_predict=12)
#define NTRK 4096
#define HIDN 1024
#define EMBN 256
#define KTOT 1280   // EMB + HID
#define NOUT 19     // 8 enc + 11 dec steps

typedef __attribute__((ext_vector_type(8))) short short8;
typedef __attribute__((ext_vector_type(4))) float f32x4;

typedef __attribute__((address_space(1))) const void GV;
typedef __attribute__((address_space(3))) void LV;

__device__ __forceinline__ uint16_t f2bf(float f) {
  uint32_t u = __float_as_uint(f);
  u += 0x7fffu + ((u >> 16) & 1u);   // round-to-nearest-even
  return (uint16_t)(u >> 16);
}
__device__ __forceinline__ float bf2f(uint16_t v) {
  return __uint_as_float(((uint32_t)v) << 16);
}
__device__ __forceinline__ float sigm(float x) { return 1.0f / (1.0f + expf(-x)); }

// -------------------------------------------------------------------------
// Weight prep: permute gate rows so new column j' = q*64 + gate*16 + l16 maps
// to original row gate*1024 + (q*16+l16). Then a 64-wide wave tile holds all
// 4 gates for 16 consecutive hidden units -> LSTM pointwise fuses in-register.
// Also builds permuted biases; dec-tag bias folds dec_wih[:,255].
// -------------------------------------------------------------------------
__global__ __launch_bounds__(256) void prep_weights(
    const float* __restrict__ encWih, const float* __restrict__ encWhh,
    const float* __restrict__ encB,
    const float* __restrict__ decWih, const float* __restrict__ decWhh,
    const float* __restrict__ decB,
    uint16_t* __restrict__ WihpE, uint16_t* __restrict__ WhhpE,
    uint16_t* __restrict__ WihpD, uint16_t* __restrict__ WhhpD,
    float* __restrict__ biasE, float* __restrict__ biasD, float* __restrict__ biasDT)
{
  const int jp = blockIdx.x;                 // permuted row 0..4095
  const int q = jp >> 6, r = jp & 63;
  const int gate = r >> 4, l16 = r & 15;
  const int u = q * 16 + l16;
  const int orig = gate * 1024 + u;
  const int t = threadIdx.x;                 // 0..255

  WihpE[(size_t)jp * 256 + t] = f2bf(encWih[(size_t)orig * 256 + t]);
  WihpD[(size_t)jp * 256 + t] = f2bf(decWih[(size_t)orig * 256 + t]);
#pragma unroll
  for (int c = 0; c < 4; c++) {
    WhhpE[(size_t)jp * 1024 + c * 256 + t] = f2bf(encWhh[(size_t)orig * 1024 + c * 256 + t]);
    WhhpD[(size_t)jp * 1024 + c * 256 + t] = f2bf(decWhh[(size_t)orig * 1024 + c * 256 + t]);
  }
  if (t == 0) {
    biasE[jp]  = encB[orig];
    biasD[jp]  = decB[orig];
    biasDT[jp] = decB[orig] + decWih[(size_t)orig * 256 + 255]; // dec tag one-hot col 255
  }
}

// Enc-tag cell with h=c=0: gates = enc_wih[:,254] + enc_b, identical for all
// tracks -> closed form h0,c0 per hidden unit.
__global__ void init_h0(const float* __restrict__ encWih, const float* __restrict__ encB,
                        float* __restrict__ h0, float* __restrict__ c0)
{
  const int u = blockIdx.x * 256 + threadIdx.x;   // 0..1023
  if (u >= 1024) return;
  const float gi = encWih[(size_t)(u) * 256 + 254]        + encB[u];
  const float gf = encWih[(size_t)(1024 + u) * 256 + 254] + encB[1024 + u];
  const float gg = encWih[(size_t)(2048 + u) * 256 + 254] + encB[2048 + u];
  const float go = encWih[(size_t)(3072 + u) * 256 + 254] + encB[3072 + u];
  (void)gf;
  const float c = sigm(gi) * tanhf(gg);   // sigm(gf)*0 + ...
  c0[u] = c;
  h0[u] = sigm(go) * tanhf(c);
}

__global__ void fill_state(const float* __restrict__ h0, const float* __restrict__ c0,
                           uint16_t* __restrict__ H, float* __restrict__ Cst)
{
  const size_t i = (size_t)blockIdx.x * 256 + threadIdx.x;  // 4096*1024 total
  const int u = (int)(i & 1023);
  H[i] = f2bf(h0[u]);
  Cst[i] = c0[u];
}

// -------------------------------------------------------------------------
// embed: x = relu(4*(o2-o1) @ emb_w.T + emb_b), cols 254/255 = 0, cast bf16
// -------------------------------------------------------------------------
__global__ __launch_bounds__(256) void embed_k(
    const float* __restrict__ o1, const float* __restrict__ o2,
    const float* __restrict__ ew, const float* __restrict__ eb,
    uint16_t* __restrict__ X)
{
  const int trk = blockIdx.x;
  const int j = threadIdx.x;
  const float vx = (o2[trk * 2]     - o1[trk * 2])     * 4.0f;
  const float vy = (o2[trk * 2 + 1] - o1[trk * 2 + 1]) * 4.0f;
  float e = 0.f;
  if (j < 254) e = fmaxf(vx * ew[j * 2] + vy * ew[j * 2 + 1] + eb[j], 0.f);
  X[(size_t)trk * 256 + j] = f2bf(e);
}

// -------------------------------------------------------------------------
// Fused LSTM-cell GEMM: G = [X|H] @ [Wih|Whh]^T (permuted) + bias, then the
// gated update in the epilogue. 128x128 tile, BK=64, 4 waves (2x2 of 64x64),
// mfma_f32_16x16x32_bf16, global_load_lds width 16 (m97 structure).
// k0=256 skips the X segment (tag step). C is fp32 in-place; H double-buffered.
// -------------------------------------------------------------------------
__global__ __launch_bounds__(256) void gemm_lstm(
    const uint16_t* __restrict__ X,   const uint16_t* __restrict__ Hin,
    const uint16_t* __restrict__ Wih, const uint16_t* __restrict__ Whh,
    const float* __restrict__ bias,   float* __restrict__ Cst,
    uint16_t* __restrict__ Hout,
    const float* __restrict__ obs1,   const float* __restrict__ obs2,
    int k0, int maskmode)
{
  __shared__ uint16_t As[128 * 64];
  __shared__ uint16_t Bs[128 * 64];
  __shared__ uint8_t  smask[128];

  const int tid  = threadIdx.x;
  const int wave = tid >> 6;
  const int lane = tid & 63;
  const int bm = blockIdx.y * 128;   // track rows
  const int bn = blockIdx.x * 128;   // permuted gate cols

  if (tid < 128) {
    bool m = true;
    if (maskmode) {
      const int row = bm + tid;
      const float a = obs1[row * 2];
      const float b = obs2[row * 2];
      m = !((a != a) || (b != b));
    }
    smask[tid] = m ? 1 : 0;
  }

  const int wrow = wave >> 1;
  const int wcol = wave & 1;
  const int quad = lane >> 4;
  const int l15  = lane & 15;
  const int lr = lane >> 3;          // row within 8-row staging chunk
  const int lc = (lane & 7) * 8;     // k-offset (elements) within chunk row

  f32x4 acc[4][4];
#pragma unroll
  for (int i = 0; i < 4; i++)
#pragma unroll
    for (int j = 0; j < 4; j++) acc[i][j] = (f32x4){0.f, 0.f, 0.f, 0.f};

  for (int kt = k0; kt < KTOT; kt += 64) {
    __syncthreads();
    // stage 16KB A + 16KB B: 32 chunks of 8 rows; each wave issues 8
    // global_load_lds_dwordx4 (lane i lands at ldsbase + i*16 by HW rule)
#pragma unroll
    for (int cc = 0; cc < 8; cc++) {
      const int chunk = cc * 4 + wave;                       // 0..31
      const bool isA = chunk < 16;
      const int trow = (isA ? chunk : chunk - 16) * 8;       // tile row base
      const int grow = (isA ? bm : bn) + trow + lr;
      const int kg = kt + lc;
      const uint16_t* gsrc;
      if (kg < 256) gsrc = (isA ? X : Wih) + (size_t)grow * 256 + kg;
      else          gsrc = (isA ? Hin : Whh) + (size_t)grow * 1024 + (kg - 256);
      uint16_t* lbase = (isA ? As : Bs) + trow * 64;
      __builtin_amdgcn_global_load_lds((GV*)gsrc, (LV*)lbase, 16, 0, 0);
    }
    __syncthreads();

#pragma unroll
    for (int kk = 0; kk < 64; kk += 32) {
      short8 af[4], bf[4];
      const int ak = kk + quad * 8;
#pragma unroll
      for (int i = 0; i < 4; i++) {
        af[i] = *(const short8*)(As + (wrow * 64 + i * 16 + l15) * 64 + ak);
        bf[i] = *(const short8*)(Bs + (wcol * 64 + i * 16 + l15) * 64 + ak);
      }
#pragma unroll
      for (int i = 0; i < 4; i++)
#pragma unroll
        for (int j = 0; j < 4; j++)
          acc[i][j] = __builtin_amdgcn_mfma_f32_16x16x32_bf16(af[i], bf[j], acc[i][j], 0, 0, 0);
    }
  }

  // Epilogue: ni tile 0..3 = gate i,f,g,o for units ((bn>>6)+wcol)*16 + l15.
  // C/D layout: col = lane&15, row = quad*4 + reg  [m89-verified]
  const int u  = ((bn >> 6) + wcol) * 16 + l15;
  const int jb = bn + wcol * 64 + l15;
  const float b_i = bias[jb];
  const float b_f = bias[jb + 16];
  const float b_g = bias[jb + 32];
  const float b_o = bias[jb + 48];

#pragma unroll
  for (int mi = 0; mi < 4; mi++) {
#pragma unroll
    for (int r = 0; r < 4; r++) {
      const int row = bm + wrow * 64 + mi * 16 + quad * 4 + r;
      const size_t idx = (size_t)row * 1024 + u;
      uint16_t hv;
      if (smask[row - bm]) {
        const float gi = acc[mi][0][r] + b_i;
        const float gf = acc[mi][1][r] + b_f;
        const float gg = acc[mi][2][r] + b_g;
        const float go = acc[mi][3][r] + b_o;
        const float cn = sigm(gf) * Cst[idx] + sigm(gi) * tanhf(gg);
        Cst[idx] = cn;
        hv = f2bf(sigm(go) * tanhf(cn));
      } else {
        hv = Hin[idx];        // state frozen; Hout is a different buffer
      }
      Hout[idx] = hv;
    }
  }
}

// -------------------------------------------------------------------------
// h2n + outputs: raw = h @ h2n_w.T + h2n_b (one wave per track), normal =
// [raw0, raw1, .01+.2*sig, .01+.2*sig, .7*sig] (NaN if masked), pos = obs2 +
// normal[:2]. Writes rel_pred and positions (positions also feed the decoder).
// -------------------------------------------------------------------------
__global__ __launch_bounds__(256) void h2n_pos(
    const uint16_t* __restrict__ H, const float* __restrict__ w5, const float* __restrict__ b5,
    const float* __restrict__ obs1, const float* __restrict__ obs2,
    float* __restrict__ outrel, float* __restrict__ outpos)
{
  const int lane  = threadIdx.x & 63;
  const int track = blockIdx.x * 4 + (threadIdx.x >> 6);

  const uint16_t* hrow = H + (size_t)track * 1024 + lane * 16;
  const short8 v0 = *(const short8*)(hrow);
  const short8 v1 = *(const short8*)(hrow + 8);
  float hv[16];
#pragma unroll
  for (int j = 0; j < 8; j++) {
    hv[j]     = bf2f((uint16_t)v0[j]);
    hv[8 + j] = bf2f((uint16_t)v1[j]);
  }
  const int kb = lane * 16;
  float p[5];
#pragma unroll
  for (int o = 0; o < 5; o++) {
    const float* wr = w5 + (size_t)o * 1024 + kb;
    float s = 0.f;
#pragma unroll
    for (int j = 0; j < 16; j++) s += hv[j] * wr[j];
    p[o] = s;
  }
#pragma unroll
  for (int o = 0; o < 5; o++) {
    float v = p[o];
    v += __shfl_xor(v, 32); v += __shfl_xor(v, 16); v += __shfl_xor(v, 8);
    v += __shfl_xor(v, 4);  v += __shfl_xor(v, 2);  v += __shfl_xor(v, 1);
    p[o] = v;
  }
  if (lane == 0) {
    const float o1x = obs1[track * 2];
    const float o2x = obs2[track * 2];
    const float o2y = obs2[track * 2 + 1];
    const bool msk = !((o1x != o1x) || (o2x != o2x));
    float n0 = p[0] + b5[0];
    float n1 = p[1] + b5[1];
    float n2 = 0.01f + 0.2f * sigm(p[2] + b5[2]);
    float n3 = 0.01f + 0.2f * sigm(p[3] + b5[3]);
    float n4 = 0.7f  * sigm(p[4] + b5[4]);
    if (!msk) {
      const float qn = __uint_as_float(0x7fc00000u);
      n0 = n1 = n2 = n3 = n4 = qn;
    }
    float* rr = outrel + (size_t)track * 5;
    rr[0] = n0; rr[1] = n1; rr[2] = n2; rr[3] = n3; rr[4] = n4;
    outpos[track * 2]     = o2x + n0;
    outpos[track * 2 + 1] = o2y + n1;
  }
}

// -------------------------------------------------------------------------
extern "C" void kernel_launch(void* const* d_in, const int* in_sizes, int n_in,
                              void* d_out, int out_size, void* d_ws, size_t ws_size,
                              hipStream_t stream)
{
  const float* observed = (const float*)d_in[0];
  const float* emb_w    = (const float*)d_in[1];
  const float* emb_b    = (const float*)d_in[2];
  const float* enc_wih  = (const float*)d_in[3];
  const float* enc_whh  = (const float*)d_in[4];
  const float* enc_b    = (const float*)d_in[5];
  const float* dec_wih  = (const float*)d_in[6];
  const float* dec_whh  = (const float*)d_in[7];
  const float* dec_b    = (const float*)d_in[8];
  const float* h2n_w    = (const float*)d_in[9];
  const float* h2n_b    = (const float*)d_in[10];
  // d_in[11] = n_predict (==12, fixed by setup)

  char* ws = (char*)d_ws;
  size_t off = 0;
  auto alloc = [&](size_t bytes) -> void* {
    size_t cur = (off + 255) & ~(size_t)255;
    off = cur + bytes;
    return (void*)(ws + cur);
  };
  uint16_t* WihpE = (uint16_t*)alloc((size_t)4096 * 256 * 2);
  uint16_t* WhhpE = (uint16_t*)alloc((size_t)4096 * 1024 * 2);
  uint16_t* WihpD = (uint16_t*)alloc((size_t)4096 * 256 * 2);
  uint16_t* WhhpD = (uint16_t*)alloc((size_t)4096 * 1024 * 2);
  float*    biasE = (float*)alloc(4096 * 4);
  float*    biasD = (float*)alloc(4096 * 4);
  float*    biasDT= (float*)alloc(4096 * 4);
  float*    h0    = (float*)alloc(1024 * 4);
  float*    c0    = (float*)alloc(1024 * 4);
  uint16_t* HA    = (uint16_t*)alloc((size_t)4096 * 1024 * 2);
  uint16_t* HB    = (uint16_t*)alloc((size_t)4096 * 1024 * 2);
  float*    Cst   = (float*)alloc((size_t)4096 * 1024 * 4);
  uint16_t* Xb    = (uint16_t*)alloc((size_t)4096 * 256 * 2);

  float* outrel = (float*)d_out;                     // (19, 4096, 5)
  float* outpos = outrel + (size_t)NOUT * 4096 * 5;  // (19, 4096, 2)

  prep_weights<<<4096, 256, 0, stream>>>(enc_wih, enc_whh, enc_b, dec_wih, dec_whh, dec_b,
                                         WihpE, WhhpE, WihpD, WhhpD, biasE, biasD, biasDT);
  init_h0<<<4, 256, 0, stream>>>(enc_wih, enc_b, h0, c0);
  fill_state<<<16384, 256, 0, stream>>>(h0, c0, HA, Cst);

  uint16_t* Hin = HA;
  uint16_t* Hout = HB;
  const dim3 ggrid(32, 32);

  // ---- encoder: 8 steps over observed pairs ----
  for (int t = 0; t < 8; t++) {
    const float* o1 = observed + (size_t)t * 4096 * 2;
    const float* o2 = observed + (size_t)(t + 1) * 4096 * 2;
    embed_k<<<4096, 256, 0, stream>>>(o1, o2, emb_w, emb_b, Xb);
    gemm_lstm<<<ggrid, 256, 0, stream>>>(Xb, Hin, WihpE, WhhpE, biasE, Cst, Hout, o1, o2, 0, 1);
    h2n_pos<<<1024, 256, 0, stream>>>(Hout, h2n_w, h2n_b, o1, o2,
                                      outrel + (size_t)t * 4096 * 5,
                                      outpos + (size_t)t * 4096 * 2);
    uint16_t* tmp = Hin; Hin = Hout; Hout = tmp;
  }

  // ---- decoder tag cell (unconditional, x one-hot folded into biasDT) ----
  gemm_lstm<<<ggrid, 256, 0, stream>>>(nullptr, Hin, WihpD, WhhpD, biasDT, Cst, Hout,
                                       nullptr, nullptr, 256, 0);
  { uint16_t* tmp = Hin; Hin = Hout; Hout = tmp; }

  // ---- decoder: 11 steps, positions fed back from d_out ----
  for (int s = 0; s < 11; s++) {
    const float* p1 = outpos + (size_t)(6 + s) * 4096 * 2;
    const float* p2 = outpos + (size_t)(7 + s) * 4096 * 2;
    embed_k<<<4096, 256, 0, stream>>>(p1, p2, emb_w, emb_b, Xb);
    gemm_lstm<<<ggrid, 256, 0, stream>>>(Xb, Hin, WihpD, WhhpD, biasD, Cst, Hout, p1, p2, 0, 1);
    h2n_pos<<<1024, 256, 0, stream>>>(Hout, h2n_w, h2n_b, p1, p2,
                                      outrel + (size_t)(8 + s) * 4096 * 5,
                                      outpos + (size_t)(8 + s) * 4096 * 2);
    uint16_t* tmp = Hin; Hin = Hout; Hout = tmp;
  }
}

// Round 2
// 1542.292 us; speedup vs baseline: 1.2013x; 1.2013x over previous
//
#include <hip/hip_runtime.h>
#include <stdint.h>

// Problem constants (reference: EMB=256, HID=1024, N_TRACKS=4096, SEQ=9, n_predict=12)
#define NTRK 4096
#define HIDN 1024
#define EMBN 256
#define KTOT 1280   // EMB + HID
#define NOUT 19     // 8 enc + 11 dec steps

typedef __attribute__((ext_vector_type(8))) short short8;
typedef __attribute__((ext_vector_type(4))) float f32x4;

typedef __attribute__((address_space(1))) const void GV;
typedef __attribute__((address_space(3))) void LV;

__device__ __forceinline__ uint16_t f2bf(float f) {
  uint32_t u = __float_as_uint(f);
  u += 0x7fffu + ((u >> 16) & 1u);   // round-to-nearest-even
  return (uint16_t)(u >> 16);
}
__device__ __forceinline__ float bf2f(uint16_t v) {
  return __uint_as_float(((uint32_t)v) << 16);
}
__device__ __forceinline__ float sigm(float x) { return 1.0f / (1.0f + expf(-x)); }

// -------------------------------------------------------------------------
// Weight prep: permute gate rows so new column j' = q*64 + gate*16 + l16 maps
// to original row gate*1024 + (q*16+l16). Then a 64-wide wave tile holds all
// 4 gates for 16 consecutive hidden units -> LSTM pointwise fuses in-register.
// -------------------------------------------------------------------------
__global__ __launch_bounds__(256) void prep_weights(
    const float* __restrict__ encWih, const float* __restrict__ encWhh,
    const float* __restrict__ encB,
    const float* __restrict__ decWih, const float* __restrict__ decWhh,
    const float* __restrict__ decB,
    uint16_t* __restrict__ WihpE, uint16_t* __restrict__ WhhpE,
    uint16_t* __restrict__ WihpD, uint16_t* __restrict__ WhhpD,
    float* __restrict__ biasE, float* __restrict__ biasD, float* __restrict__ biasDT)
{
  const int jp = blockIdx.x;                 // permuted row 0..4095
  const int q = jp >> 6, r = jp & 63;
  const int gate = r >> 4, l16 = r & 15;
  const int u = q * 16 + l16;
  const int orig = gate * 1024 + u;
  const int t = threadIdx.x;                 // 0..255

  WihpE[(size_t)jp * 256 + t] = f2bf(encWih[(size_t)orig * 256 + t]);
  WihpD[(size_t)jp * 256 + t] = f2bf(decWih[(size_t)orig * 256 + t]);
#pragma unroll
  for (int c = 0; c < 4; c++) {
    WhhpE[(size_t)jp * 1024 + c * 256 + t] = f2bf(encWhh[(size_t)orig * 1024 + c * 256 + t]);
    WhhpD[(size_t)jp * 1024 + c * 256 + t] = f2bf(decWhh[(size_t)orig * 1024 + c * 256 + t]);
  }
  if (t == 0) {
    biasE[jp]  = encB[orig];
    biasD[jp]  = decB[orig];
    biasDT[jp] = decB[orig] + decWih[(size_t)orig * 256 + 255]; // dec tag one-hot col 255
  }
}

// Enc-tag cell with h=c=0: gates = enc_wih[:,254] + enc_b, identical for all
// tracks -> closed form h0,c0 per hidden unit.
__global__ void init_h0(const float* __restrict__ encWih, const float* __restrict__ encB,
                        float* __restrict__ h0, float* __restrict__ c0)
{
  const int u = blockIdx.x * 256 + threadIdx.x;   // 0..1023
  if (u >= 1024) return;
  const float gi = encWih[(size_t)(u) * 256 + 254]        + encB[u];
  const float gg = encWih[(size_t)(2048 + u) * 256 + 254] + encB[2048 + u];
  const float go = encWih[(size_t)(3072 + u) * 256 + 254] + encB[3072 + u];
  const float c = sigm(gi) * tanhf(gg);   // sigm(gf)*0 + ...
  c0[u] = c;
  h0[u] = sigm(go) * tanhf(c);
}

__global__ void fill_state(const float* __restrict__ h0, const float* __restrict__ c0,
                           uint16_t* __restrict__ H, float* __restrict__ Cst)
{
  const size_t i = (size_t)blockIdx.x * 256 + threadIdx.x;  // 4096*1024 total
  const int u = (int)(i & 1023);
  H[i] = f2bf(h0[u]);
  Cst[i] = c0[u];
}

// -------------------------------------------------------------------------
// embed: x = relu(4*(o2-o1) @ emb_w.T + emb_b), cols 254/255 = 0, cast bf16
// -------------------------------------------------------------------------
__global__ __launch_bounds__(256) void embed_k(
    const float* __restrict__ o1, const float* __restrict__ o2,
    const float* __restrict__ ew, const float* __restrict__ eb,
    uint16_t* __restrict__ X)
{
  const int trk = blockIdx.x;
  const int j = threadIdx.x;
  const float vx = (o2[trk * 2]     - o1[trk * 2])     * 4.0f;
  const float vy = (o2[trk * 2 + 1] - o1[trk * 2 + 1]) * 4.0f;
  float e = 0.f;
  if (j < 254) e = fmaxf(vx * ew[j * 2] + vy * ew[j * 2 + 1] + eb[j], 0.f);
  X[(size_t)trk * 256 + j] = f2bf(e);
}

// -------------------------------------------------------------------------
// Fused LSTM-cell GEMM: G = [X|H] @ [Wih|Whh]^T (permuted) + bias, gated
// update in the epilogue. 128x128 tile, BK=64, 4 waves (2x2 of 64x64),
// mfma_f32_16x16x32_bf16, global_load_lds width 16.
//
// LDS bank-conflict fix (R1): row stride is 128B = one bank wrap, so the
// plain layout puts all 16 rows of a ds_read_b128 on one 4-bank group
// (16-way). We XOR-swizzle the 16B k-chunk index by (row & 7): staging lane
// (r = lane>>3, j = lane&7) fetches GLOBAL chunk j^r (LDS dest is fixed by
// global_load_lds at lane*16); the read side uses chunk ((kk>>3)+quad)^(row&7).
// Result: each b128 wave access spreads 8 lanes per 4-bank group = the
// 1KiB/128B-per-cycle floor.
// -------------------------------------------------------------------------
__global__ __launch_bounds__(256) void gemm_lstm(
    const uint16_t* __restrict__ X,   const uint16_t* __restrict__ Hin,
    const uint16_t* __restrict__ Wih, const uint16_t* __restrict__ Whh,
    const float* __restrict__ bias,   float* __restrict__ Cst,
    uint16_t* __restrict__ Hout,
    const float* __restrict__ obs1,   const float* __restrict__ obs2,
    int k0, int maskmode)
{
  __shared__ uint16_t As[128 * 64];
  __shared__ uint16_t Bs[128 * 64];
  __shared__ uint8_t  smask[128];

  const int tid  = threadIdx.x;
  const int wave = tid >> 6;
  const int lane = tid & 63;
  const int bm = blockIdx.y * 128;   // track rows
  const int bn = blockIdx.x * 128;   // permuted gate cols

  if (tid < 128) {
    bool m = true;
    if (maskmode) {
      const int row = bm + tid;
      const float a = obs1[row * 2];
      const float b = obs2[row * 2];
      m = !((a != a) || (b != b));
    }
    smask[tid] = m ? 1 : 0;
  }

  const int wrow = wave >> 1;
  const int wcol = wave & 1;
  const int quad = lane >> 4;
  const int l15  = lane & 15;
  const int m7   = l15 & 7;
  const int lr = lane >> 3;                  // row within 8-row staging chunk
  const int lj = ((lane & 7) ^ lr) * 8;      // swizzled global k-offset (elements)

  f32x4 acc[4][4];
#pragma unroll
  for (int i = 0; i < 4; i++)
#pragma unroll
    for (int j = 0; j < 4; j++) acc[i][j] = (f32x4){0.f, 0.f, 0.f, 0.f};

  auto mfma_slab = [&]() {
#pragma unroll
    for (int kk = 0; kk < 64; kk += 32) {
      short8 af[4], bf[4];
      const int jc = (((kk >> 3) + quad) ^ m7) * 8;   // swizzled read chunk
#pragma unroll
      for (int i = 0; i < 4; i++) {
        af[i] = *(const short8*)(As + (wrow * 64 + i * 16 + l15) * 64 + jc);
        bf[i] = *(const short8*)(Bs + (wcol * 64 + i * 16 + l15) * 64 + jc);
      }
#pragma unroll
      for (int i = 0; i < 4; i++)
#pragma unroll
        for (int j = 0; j < 4; j++)
          acc[i][j] = __builtin_amdgcn_mfma_f32_16x16x32_bf16(af[i], bf[j], acc[i][j], 0, 0, 0);
    }
  };

  // ---- phase A: X | Wih segment (row stride 256), skipped for tag step ----
  if (k0 == 0) {
    for (int kt = 0; kt < 256; kt += 64) {
      __syncthreads();
#pragma unroll
      for (int cc = 0; cc < 8; cc++) {
        const bool isA = cc < 4;
        const int trow = ((cc & 3) * 4 + wave) * 8;
        const int grow = (isA ? bm : bn) + trow + lr;
        const uint16_t* gsrc = (isA ? X : Wih) + (size_t)grow * 256 + (kt + lj);
        uint16_t* lbase = (isA ? As : Bs) + trow * 64;
        __builtin_amdgcn_global_load_lds((GV*)gsrc, (LV*)lbase, 16, 0, 0);
      }
      __syncthreads();
      mfma_slab();
    }
  }

  // ---- phase B: Hin | Whh segment (row stride 1024) ----
  for (int kt = 0; kt < 1024; kt += 64) {
    __syncthreads();
#pragma unroll
    for (int cc = 0; cc < 8; cc++) {
      const bool isA = cc < 4;
      const int trow = ((cc & 3) * 4 + wave) * 8;
      const int grow = (isA ? bm : bn) + trow + lr;
      const uint16_t* gsrc = (isA ? Hin : Whh) + (size_t)grow * 1024 + (kt + lj);
      uint16_t* lbase = (isA ? As : Bs) + trow * 64;
      __builtin_amdgcn_global_load_lds((GV*)gsrc, (LV*)lbase, 16, 0, 0);
    }
    __syncthreads();
    mfma_slab();
  }

  // Epilogue: ni tile 0..3 = gate i,f,g,o for units ((bn>>6)+wcol)*16 + l15.
  // C/D layout: col = lane&15, row = quad*4 + reg  [m89-verified]
  const int u  = ((bn >> 6) + wcol) * 16 + l15;
  const int jb = bn + wcol * 64 + l15;
  const float b_i = bias[jb];
  const float b_f = bias[jb + 16];
  const float b_g = bias[jb + 32];
  const float b_o = bias[jb + 48];

#pragma unroll
  for (int mi = 0; mi < 4; mi++) {
#pragma unroll
    for (int r = 0; r < 4; r++) {
      const int row = bm + wrow * 64 + mi * 16 + quad * 4 + r;
      const size_t idx = (size_t)row * 1024 + u;
      uint16_t hv;
      if (smask[row - bm]) {
        const float gi = acc[mi][0][r] + b_i;
        const float gf = acc[mi][1][r] + b_f;
        const float gg = acc[mi][2][r] + b_g;
        const float go = acc[mi][3][r] + b_o;
        const float cn = sigm(gf) * Cst[idx] + sigm(gi) * tanhf(gg);
        Cst[idx] = cn;
        hv = f2bf(sigm(go) * tanhf(cn));
      } else {
        hv = Hin[idx];        // state frozen; Hout is a different buffer
      }
      Hout[idx] = hv;
    }
  }
}

// -------------------------------------------------------------------------
// h2n + outputs: raw = h @ h2n_w.T + h2n_b (one wave per track)
// -------------------------------------------------------------------------
__global__ __launch_bounds__(256) void h2n_pos(
    const uint16_t* __restrict__ H, const float* __restrict__ w5, const float* __restrict__ b5,
    const float* __restrict__ obs1, const float* __restrict__ obs2,
    float* __restrict__ outrel, float* __restrict__ outpos)
{
  const int lane  = threadIdx.x & 63;
  const int track = blockIdx.x * 4 + (threadIdx.x >> 6);

  const uint16_t* hrow = H + (size_t)track * 1024 + lane * 16;
  const short8 v0 = *(const short8*)(hrow);
  const short8 v1 = *(const short8*)(hrow + 8);
  float hv[16];
#pragma unroll
  for (int j = 0; j < 8; j++) {
    hv[j]     = bf2f((uint16_t)v0[j]);
    hv[8 + j] = bf2f((uint16_t)v1[j]);
  }
  const int kb = lane * 16;
  float p[5];
#pragma unroll
  for (int o = 0; o < 5; o++) {
    const float* wr = w5 + (size_t)o * 1024 + kb;
    float s = 0.f;
#pragma unroll
    for (int j = 0; j < 16; j++) s += hv[j] * wr[j];
    p[o] = s;
  }
#pragma unroll
  for (int o = 0; o < 5; o++) {
    float v = p[o];
    v += __shfl_xor(v, 32); v += __shfl_xor(v, 16); v += __shfl_xor(v, 8);
    v += __shfl_xor(v, 4);  v += __shfl_xor(v, 2);  v += __shfl_xor(v, 1);
    p[o] = v;
  }
  if (lane == 0) {
    const float o1x = obs1[track * 2];
    const float o2x = obs2[track * 2];
    const float o2y = obs2[track * 2 + 1];
    const bool msk = !((o1x != o1x) || (o2x != o2x));
    float n0 = p[0] + b5[0];
    float n1 = p[1] + b5[1];
    float n2 = 0.01f + 0.2f * sigm(p[2] + b5[2]);
    float n3 = 0.01f + 0.2f * sigm(p[3] + b5[3]);
    float n4 = 0.7f  * sigm(p[4] + b5[4]);
    if (!msk) {
      const float qn = __uint_as_float(0x7fc00000u);
      n0 = n1 = n2 = n3 = n4 = qn;
    }
    float* rr = outrel + (size_t)track * 5;
    rr[0] = n0; rr[1] = n1; rr[2] = n2; rr[3] = n3; rr[4] = n4;
    outpos[track * 2]     = o2x + n0;
    outpos[track * 2 + 1] = o2y + n1;
  }
}

// -------------------------------------------------------------------------
extern "C" void kernel_launch(void* const* d_in, const int* in_sizes, int n_in,
                              void* d_out, int out_size, void* d_ws, size_t ws_size,
                              hipStream_t stream)
{
  const float* observed = (const float*)d_in[0];
  const float* emb_w    = (const float*)d_in[1];
  const float* emb_b    = (const float*)d_in[2];
  const float* enc_wih  = (const float*)d_in[3];
  const float* enc_whh  = (const float*)d_in[4];
  const float* enc_b    = (const float*)d_in[5];
  const float* dec_wih  = (const float*)d_in[6];
  const float* dec_whh  = (const float*)d_in[7];
  const float* dec_b    = (const float*)d_in[8];
  const float* h2n_w    = (const float*)d_in[9];
  const float* h2n_b    = (const float*)d_in[10];
  // d_in[11] = n_predict (==12, fixed by setup)

  char* ws = (char*)d_ws;
  size_t off = 0;
  auto alloc = [&](size_t bytes) -> void* {
    size_t cur = (off + 255) & ~(size_t)255;
    off = cur + bytes;
    return (void*)(ws + cur);
  };
  uint16_t* WihpE = (uint16_t*)alloc((size_t)4096 * 256 * 2);
  uint16_t* WhhpE = (uint16_t*)alloc((size_t)4096 * 1024 * 2);
  uint16_t* WihpD = (uint16_t*)alloc((size_t)4096 * 256 * 2);
  uint16_t* WhhpD = (uint16_t*)alloc((size_t)4096 * 1024 * 2);
  float*    biasE = (float*)alloc(4096 * 4);
  float*    biasD = (float*)alloc(4096 * 4);
  float*    biasDT= (float*)alloc(4096 * 4);
  float*    h0    = (float*)alloc(1024 * 4);
  float*    c0    = (float*)alloc(1024 * 4);
  uint16_t* HA    = (uint16_t*)alloc((size_t)4096 * 1024 * 2);
  uint16_t* HB    = (uint16_t*)alloc((size_t)4096 * 1024 * 2);
  float*    Cst   = (float*)alloc((size_t)4096 * 1024 * 4);
  uint16_t* Xb    = (uint16_t*)alloc((size_t)4096 * 256 * 2);

  float* outrel = (float*)d_out;                     // (19, 4096, 5)
  float* outpos = outrel + (size_t)NOUT * 4096 * 5;  // (19, 4096, 2)

  prep_weights<<<4096, 256, 0, stream>>>(enc_wih, enc_whh, enc_b, dec_wih, dec_whh, dec_b,
                                         WihpE, WhhpE, WihpD, WhhpD, biasE, biasD, biasDT);
  init_h0<<<4, 256, 0, stream>>>(enc_wih, enc_b, h0, c0);
  fill_state<<<16384, 256, 0, stream>>>(h0, c0, HA, Cst);

  uint16_t* Hin = HA;
  uint16_t* Hout = HB;
  const dim3 ggrid(32, 32);

  // ---- encoder: 8 steps over observed pairs ----
  for (int t = 0; t < 8; t++) {
    const float* o1 = observed + (size_t)t * 4096 * 2;
    const float* o2 = observed + (size_t)(t + 1) * 4096 * 2;
    embed_k<<<4096, 256, 0, stream>>>(o1, o2, emb_w, emb_b, Xb);
    gemm_lstm<<<ggrid, 256, 0, stream>>>(Xb, Hin, WihpE, WhhpE, biasE, Cst, Hout, o1, o2, 0, 1);
    h2n_pos<<<1024, 256, 0, stream>>>(Hout, h2n_w, h2n_b, o1, o2,
                                      outrel + (size_t)t * 4096 * 5,
                                      outpos + (size_t)t * 4096 * 2);
    uint16_t* tmp = Hin; Hin = Hout; Hout = tmp;
  }

  // ---- decoder tag cell (unconditional, x one-hot folded into biasDT) ----
  gemm_lstm<<<ggrid, 256, 0, stream>>>(nullptr, Hin, WihpD, WhhpD, biasDT, Cst, Hout,
                                       nullptr, nullptr, 256, 0);
  { uint16_t* tmp = Hin; Hin = Hout; Hout = tmp; }

  // ---- decoder: 11 steps, positions fed back from d_out ----
  for (int s = 0; s < 11; s++) {
    const float* p1 = outpos + (size_t)(6 + s) * 4096 * 2;
    const float* p2 = outpos + (size_t)(7 + s) * 4096 * 2;
    embed_k<<<4096, 256, 0, stream>>>(p1, p2, emb_w, emb_b, Xb);
    gemm_lstm<<<ggrid, 256, 0, stream>>>(Xb, Hin, WihpD, WhhpD, biasD, Cst, Hout, p1, p2, 0, 1);
    h2n_pos<<<1024, 256, 0, stream>>>(Hout, h2n_w, h2n_b, p1, p2,
                                      outrel + (size_t)(8 + s) * 4096 * 5,
                                      outpos + (size_t)(8 + s) * 4096 * 2);
    uint16_t* tmp = Hin; Hin = Hout; Hout = tmp;
  }
}